// Round 2
// baseline (15440.244 us; speedup 1.0000x reference)
//
#include <hip/hip_runtime.h>
#include <hip/hip_bf16.h>
#include <hip/hip_cooperative_groups.h>

namespace cg = cooperative_groups;

#define B_   64
#define T_   128
#define IN_  1024
#define H_   2048
#define H4_  8192
#define BT_  8192                 // B_*T_
#define BTH_ 16777216LL           // B_*T_*H_

typedef __attribute__((ext_vector_type(8))) short short8;   // 8 bf16 = 4 VGPRs
typedef __attribute__((ext_vector_type(4))) float f32x4;

__device__ __forceinline__ unsigned short f32_to_bf16_rne(float f) {
    union { float f; unsigned int u; } v; v.f = f;
    return (unsigned short)((v.u + 0x7fffu + ((v.u >> 16) & 1u)) >> 16);
}

// async global->LDS, 16B per lane. LDS dest = wave-uniform base + lane*16.
__device__ __forceinline__ void gload_lds16(const unsigned short* g, unsigned short* l) {
    __builtin_amdgcn_global_load_lds(
        (const __attribute__((address_space(1))) unsigned int*)g,
        (__attribute__((address_space(3))) unsigned int*)l,
        16, 0, 0);
}

// ---------- fp32 -> bf16 conversion (vectorized, grid-stride) ----------
__global__ void cvt_bf16_kernel(const float* __restrict__ src,
                                unsigned short* __restrict__ dst, long n) {
    long i = ((long)blockIdx.x * blockDim.x + threadIdx.x) * 4;
    long stride = (long)gridDim.x * blockDim.x * 4;
    for (; i < n; i += stride) {
        float4 v = *reinterpret_cast<const float4*>(src + i);
        ushort4 o;
        o.x = f32_to_bf16_rne(v.x);
        o.y = f32_to_bf16_rne(v.y);
        o.z = f32_to_bf16_rne(v.z);
        o.w = f32_to_bf16_rne(v.w);
        *reinterpret_cast<ushort4*>(dst + i) = o;
    }
}

// ---------- Phase 1: Yx = x @ Wx^T + b  (128x128 LDS-staged GEMM) ----------
// 256 threads = 4 waves (2x2). Wave tile 64x64 = 4x4 MFMA 16x16x32 acc.
// LDS 16B-unit XOR swizzle (u ^= (row>>1)&3): staging pre-swizzles the GLOBAL
// source (linear global_load_lds dest, rule both-sides-or-neither); frag reads
// apply the same XOR -> 8-way bank conflict becomes 2-way (free).
__global__ __launch_bounds__(256) void gemm_yx(
    const unsigned short* __restrict__ Xb,    // [BT_, IN_] bf16
    const unsigned short* __restrict__ Wxb,   // [H4_, IN_] bf16
    const float* __restrict__ bias,           // [H4_]
    float* __restrict__ out)                  // d_out base
{
    int bid = blockIdx.x;
    int sw  = (bid & 7) * 512 + (bid >> 3);   // XCD-aware, bijective (4096%8==0)
    int nb  = sw & 63;
    int mb  = sw >> 6;
    int m0  = mb * 128;
    int n0  = nb * 128;

    int tid  = threadIdx.x;
    int wave = tid >> 6;
    int lane = tid & 63;
    int col  = lane & 15;
    int quad = lane >> 4;
    int wm   = wave >> 1;
    int wn   = wave & 1;

    __shared__ unsigned short As[128 * 32];   // 8 KB
    __shared__ unsigned short Bs[128 * 32];   // 8 KB

    f32x4 acc[4][4];
#pragma unroll
    for (int i = 0; i < 4; i++)
#pragma unroll
        for (int j = 0; j < 4; j++) acc[i][j] = (f32x4){0.f, 0.f, 0.f, 0.f};

    for (int k0 = 0; k0 < IN_; k0 += 32) {
        // ---- stage: each thread 2x16B for A, 2x16B for B, source pre-swizzled
#pragma unroll
        for (int r = 0; r < 2; r++) {
            int idx = r * 256 + tid;            // 0..511
            int row = idx >> 2;                 // 0..127
            int u   = idx & 3;                  // 16B unit in row
            int ug  = u ^ ((row >> 1) & 3);     // swizzled global unit
            int dbase = (r * 256 + wave * 64) * 8;   // wave-uniform elem base
            gload_lds16(Xb  + (size_t)(m0 + row) * IN_ + k0 + ug * 8, &As[dbase]);
            gload_lds16(Wxb + (size_t)(n0 + row) * IN_ + k0 + ug * 8, &Bs[dbase]);
        }
        __syncthreads();

        // ---- frags (swizzled read) + 16 MFMA ----
        short8 af[4], bf[4];
#pragma unroll
        for (int mt = 0; mt < 4; mt++) {
            int ra = wm * 64 + mt * 16 + col;
            af[mt] = *(const short8*)&As[ra * 32 + (quad ^ ((ra >> 1) & 3)) * 8];
        }
#pragma unroll
        for (int nt = 0; nt < 4; nt++) {
            int rb = wn * 64 + nt * 16 + col;
            bf[nt] = *(const short8*)&Bs[rb * 32 + (quad ^ ((rb >> 1) & 3)) * 8];
        }
#pragma unroll
        for (int mt = 0; mt < 4; mt++)
#pragma unroll
            for (int nt = 0; nt < 4; nt++)
                acc[mt][nt] = __builtin_amdgcn_mfma_f32_16x16x32_bf16(
                    af[mt], bf[nt], acc[mt][nt], 0, 0, 0);
        __syncthreads();
    }

    // ---- epilogue: bias add, write into yi/yf/yg/yo slabs ----
#pragma unroll
    for (int nt = 0; nt < 4; nt++) {
        int n = n0 + wn * 64 + nt * 16 + col;
        int g = n >> 11;
        int h = n & 2047;
        float bv = bias[n];
        float* slab = out + (size_t)(2 + g) * BTH_ + h;
#pragma unroll
        for (int mt = 0; mt < 4; mt++)
#pragma unroll
            for (int r = 0; r < 4; r++) {
                int m = m0 + wm * 64 + mt * 16 + quad * 4 + r;
                slab[(size_t)m * H_] = acc[mt][nt][r] + bv;
            }
    }
}

// ---------- Persistent LSTM: all 128 timesteps in ONE cooperative launch ----
// Grid: 256 blocks x 512 threads (1 block/CU). Block owns 8 hidden cols x
// 4 gates x all 64 batch rows. Wa slice (32 rows x 2048 = 128 KB) lives in
// REGISTERS: wave w = (kh = w>>1: K-quarter of 512, gp = w&1: gate pair),
// each lane holds 16 x short8 = 64 VGPR of weights, loaded once.
// Per step: 16 K-iters x 4 M-tiles MFMA (A = a_prev from L2), K-quarter
// partials reduced via LDS, fused activation; c lives in a per-thread reg.
// grid.sync() between steps (device-scope fence -> cross-XCD a visibility).
__global__ __launch_bounds__(512) void lstm_persistent(
    const unsigned short* __restrict__ Wab,   // [H4_, H_] bf16
    unsigned short* __restrict__ abuf0,       // [B_, H_] bf16 ping
    unsigned short* __restrict__ abuf1,       // [B_, H_] bf16 pong
    const float* __restrict__ c0,             // [B_, H_] fp32
    float* __restrict__ out)                  // d_out base
{
    cg::grid_group grid = cg::this_grid();

    int blk  = blockIdx.x;        // 0..255
    int h0   = blk * 8;
    int tid  = threadIdx.x;
    int w    = tid >> 6;
    int kh   = w >> 1;            // K-quarter 0..3
    int gp   = w & 1;             // gate pair 0..1
    int lane = tid & 63;
    int c    = lane & 15;         // MFMA col: gate = gp*2 + (c>>3), h = h0 + (c&7)
    int q    = lane >> 4;

    // ---- weights -> registers (once) ----
    int gate = gp * 2 + (c >> 3);
    const unsigned short* wrow =
        Wab + (size_t)(gate * H_ + h0 + (c & 7)) * H_ + kh * 512 + q * 8;
    short8 wreg[16];
#pragma unroll
    for (int kq = 0; kq < 16; kq++)
        wreg[kq] = *(const short8*)(wrow + kq * 32);

    // ---- per-thread cell: thread <-> (bb, hl) mapping is static across steps
    int bb = tid >> 3;            // 0..63
    int hl = tid & 7;             // 0..7
    float c_reg = c0[bb * H_ + h0 + hl];

    __shared__ float yt[4][2][64][17];   // [kh][gp][m][col16], +1 pad

    for (int t = 0; t < T_; ++t) {
        const unsigned short* ap = (t & 1) ? abuf1 : abuf0;
        unsigned short*       an = (t & 1) ? abuf0 : abuf1;

        // ---- y = a_prev @ Wa^T for this wave's (kh, gp) slice ----
        const unsigned short* ab = ap + (size_t)c * H_ + kh * 512 + q * 8;
        f32x4 acc[4];
#pragma unroll
        for (int mt = 0; mt < 4; mt++) acc[mt] = (f32x4){0.f, 0.f, 0.f, 0.f};

#pragma unroll
        for (int kq = 0; kq < 16; kq++) {
#pragma unroll
            for (int mt = 0; mt < 4; mt++) {
                short8 af = *(const short8*)(ab + (size_t)mt * 16 * H_ + kq * 32);
                acc[mt] = __builtin_amdgcn_mfma_f32_16x16x32_bf16(
                    af, wreg[kq], acc[mt], 0, 0, 0);
            }
        }

        // ---- K-quarter partials -> LDS ----
#pragma unroll
        for (int mt = 0; mt < 4; mt++)
#pragma unroll
            for (int r = 0; r < 4; r++)
                yt[kh][gp][mt * 16 + q * 4 + r][c] = acc[mt][r];
        __syncthreads();

        // ---- fused activation: one cell (bb, hl) per thread ----
        long long oidx = ((long long)bb * T_ + t) * H_ + h0 + hl;
        float y[4];
#pragma unroll
        for (int g2 = 0; g2 < 4; g2++) {
            int cc  = (g2 & 1) * 8 + hl;
            int gpp = g2 >> 1;
            float v = yt[0][gpp][bb][cc] + yt[1][gpp][bb][cc] +
                      yt[2][gpp][bb][cc] + yt[3][gpp][bb][cc];
            v += out[(size_t)(2 + g2) * BTH_ + oidx];   // Yx + bias (precomputed)
            out[(size_t)(2 + g2) * BTH_ + oidx] = v;
            y[g2] = v;
        }
        float si = 1.f / (1.f + __expf(-y[0]));
        float sf = 1.f / (1.f + __expf(-y[1]));
        float so = 1.f / (1.f + __expf(-y[3]));
        float tg = tanhf(y[2]);
        c_reg = sf * c_reg + si * tg;
        float at = so * tanhf(c_reg);

        out[oidx]         = at;       // a slab
        out[BTH_ + oidx]  = c_reg;    // c slab
        an[bb * H_ + h0 + hl] = f32_to_bf16_rne(at);

        __threadfence();              // device-scope release (cross-XCD)
        grid.sync();                  // all blocks advance to step t+1 together
    }
}

extern "C" void kernel_launch(void* const* d_in, const int* in_sizes, int n_in,
                              void* d_out, int out_size, void* d_ws, size_t ws_size,
                              hipStream_t stream) {
    const float* x    = (const float*)d_in[0];   // [B,T,IN]
    const float* Wx   = (const float*)d_in[1];   // [4H,IN]
    const float* Wa   = (const float*)d_in[2];   // [4H,H]
    const float* bias = (const float*)d_in[3];   // [4H]
    const float* a0   = (const float*)d_in[4];   // [B,H]
    const float* c0   = (const float*)d_in[5];   // [B,H]
    float* out = (float*)d_out;

    // workspace layout (bf16 = unsigned short)
    unsigned short* xb    = (unsigned short*)d_ws;          // BT_*IN_
    unsigned short* wxb   = xb  + (size_t)BT_ * IN_;        // H4_*IN_
    unsigned short* wab   = wxb + (size_t)H4_ * IN_;        // H4_*H_
    unsigned short* abuf0 = wab + (size_t)H4_ * H_;         // B_*H_
    unsigned short* abuf1 = abuf0 + (size_t)B_ * H_;        // B_*H_

    cvt_bf16_kernel<<<2048, 256, 0, stream>>>(x,  xb,  (long)BT_ * IN_);
    cvt_bf16_kernel<<<2048, 256, 0, stream>>>(Wx, wxb, (long)H4_ * IN_);
    cvt_bf16_kernel<<<2048, 256, 0, stream>>>(Wa, wab, (long)H4_ * H_);
    cvt_bf16_kernel<<<128,  256, 0, stream>>>(a0, abuf0, (long)B_ * H_);

    gemm_yx<<<(BT_ / 128) * (H4_ / 128), 256, 0, stream>>>(xb, wxb, bias, out);

    const unsigned short* wab_c = wab;
    const float* c0_c = c0;
    void* kargs[5];
    kargs[0] = (void*)&wab_c;
    kargs[1] = (void*)&abuf0;
    kargs[2] = (void*)&abuf1;
    kargs[3] = (void*)&c0_c;
    kargs[4] = (void*)&out;
    hipLaunchCooperativeKernel((const void*)lstm_persistent,
                               dim3(256), dim3(512), kargs, 0, stream);
}

// Round 3
// 15153.818 us; speedup vs baseline: 1.0189x; 1.0189x over previous
//
#include <hip/hip_runtime.h>
#include <hip/hip_bf16.h>
#include <hip/hip_cooperative_groups.h>

namespace cg = cooperative_groups;

#define B_   64
#define T_   128
#define IN_  1024
#define H_   2048
#define H4_  8192
#define BT_  8192                 // B_*T_
#define BTH_ 16777216LL           // B_*T_*H_

typedef __attribute__((ext_vector_type(8))) short short8;   // 8 bf16 = 4 VGPRs
typedef __attribute__((ext_vector_type(4))) float f32x4;

__device__ __forceinline__ unsigned short f32_to_bf16_rne(float f) {
    union { float f; unsigned int u; } v; v.f = f;
    return (unsigned short)((v.u + 0x7fffu + ((v.u >> 16) & 1u)) >> 16);
}

// async global->LDS, 16B per lane. LDS dest = wave-uniform base + lane*16.
__device__ __forceinline__ void gload_lds16(const unsigned short* g, unsigned short* l) {
    __builtin_amdgcn_global_load_lds(
        (const __attribute__((address_space(1))) unsigned int*)g,
        (__attribute__((address_space(3))) unsigned int*)l,
        16, 0, 0);
}

// ---------- fp32 -> bf16 conversion (vectorized, grid-stride) ----------
__global__ void cvt_bf16_kernel(const float* __restrict__ src,
                                unsigned short* __restrict__ dst, long n) {
    long i = ((long)blockIdx.x * blockDim.x + threadIdx.x) * 4;
    long stride = (long)gridDim.x * blockDim.x * 4;
    for (; i < n; i += stride) {
        float4 v = *reinterpret_cast<const float4*>(src + i);
        ushort4 o;
        o.x = f32_to_bf16_rne(v.x);
        o.y = f32_to_bf16_rne(v.y);
        o.z = f32_to_bf16_rne(v.z);
        o.w = f32_to_bf16_rne(v.w);
        *reinterpret_cast<ushort4*>(dst + i) = o;
    }
}

// ---------- Phase 1: Yx = x @ Wx^T + b  (128x128 LDS-staged GEMM) ----------
__global__ __launch_bounds__(256) void gemm_yx(
    const unsigned short* __restrict__ Xb,    // [BT_, IN_] bf16
    const unsigned short* __restrict__ Wxb,   // [H4_, IN_] bf16
    const float* __restrict__ bias,           // [H4_]
    float* __restrict__ out)                  // d_out base
{
    int bid = blockIdx.x;
    int sw  = (bid & 7) * 512 + (bid >> 3);   // XCD-aware, bijective (4096%8==0)
    int nb  = sw & 63;
    int mb  = sw >> 6;
    int m0  = mb * 128;
    int n0  = nb * 128;

    int tid  = threadIdx.x;
    int wave = tid >> 6;
    int lane = tid & 63;
    int col  = lane & 15;
    int quad = lane >> 4;
    int wm   = wave >> 1;
    int wn   = wave & 1;

    __shared__ unsigned short As[128 * 32];   // 8 KB
    __shared__ unsigned short Bs[128 * 32];   // 8 KB

    f32x4 acc[4][4];
#pragma unroll
    for (int i = 0; i < 4; i++)
#pragma unroll
        for (int j = 0; j < 4; j++) acc[i][j] = (f32x4){0.f, 0.f, 0.f, 0.f};

    for (int k0 = 0; k0 < IN_; k0 += 32) {
        // ---- stage: each thread 2x16B for A, 2x16B for B, source pre-swizzled
#pragma unroll
        for (int r = 0; r < 2; r++) {
            int idx = r * 256 + tid;            // 0..511
            int row = idx >> 2;                 // 0..127
            int u   = idx & 3;                  // 16B unit in row
            int ug  = u ^ ((row >> 1) & 3);     // swizzled global unit
            int dbase = (r * 256 + wave * 64) * 8;   // wave-uniform elem base
            gload_lds16(Xb  + (size_t)(m0 + row) * IN_ + k0 + ug * 8, &As[dbase]);
            gload_lds16(Wxb + (size_t)(n0 + row) * IN_ + k0 + ug * 8, &Bs[dbase]);
        }
        __syncthreads();

        // ---- frags (swizzled read) + 16 MFMA ----
        short8 af[4], bf[4];
#pragma unroll
        for (int mt = 0; mt < 4; mt++) {
            int ra = wm * 64 + mt * 16 + col;
            af[mt] = *(const short8*)&As[ra * 32 + (quad ^ ((ra >> 1) & 3)) * 8];
        }
#pragma unroll
        for (int nt = 0; nt < 4; nt++) {
            int rb = wn * 64 + nt * 16 + col;
            bf[nt] = *(const short8*)&Bs[rb * 32 + (quad ^ ((rb >> 1) & 3)) * 8];
        }
#pragma unroll
        for (int mt = 0; mt < 4; mt++)
#pragma unroll
            for (int nt = 0; nt < 4; nt++)
                acc[mt][nt] = __builtin_amdgcn_mfma_f32_16x16x32_bf16(
                    af[mt], bf[nt], acc[mt][nt], 0, 0, 0);
        __syncthreads();
    }

    // ---- epilogue: bias add, write into yi/yf/yg/yo slabs ----
#pragma unroll
    for (int nt = 0; nt < 4; nt++) {
        int n = n0 + wn * 64 + nt * 16 + col;
        int g = n >> 11;
        int h = n & 2047;
        float bv = bias[n];
        float* slab = out + (size_t)(2 + g) * BTH_ + h;
#pragma unroll
        for (int mt = 0; mt < 4; mt++)
#pragma unroll
            for (int r = 0; r < 4; r++) {
                int m = m0 + wm * 64 + mt * 16 + quad * 4 + r;
                slab[(size_t)m * H_] = acc[mt][nt][r] + bv;
            }
    }
}

// ---------- Persistent LSTM: all 128 timesteps in ONE cooperative launch ----
// Grid: 256 blocks x 512 threads (1 block/CU, 2 waves/EU -> 256 VGPR budget).
// Block owns 8 hidden cols x 4 gates x all 64 batch rows. Wa slice lives in
// REGISTERS: wave w = (kh = w>>1: K-quarter, gp = w&1: gate pair), each lane
// holds 16 x short8 = 64 VGPR of weights, loaded once.
// __launch_bounds__(512, 2): round-2's (512) default capped VGPR at 64 ->
// wreg spilled to scratch -> 115 us/step. 2 waves/EU allows 256 VGPR/wave.
__global__ __launch_bounds__(512, 2) void lstm_persistent(
    const unsigned short* __restrict__ Wab,   // [H4_, H_] bf16
    unsigned short* __restrict__ abuf0,       // [B_, H_] bf16 ping
    unsigned short* __restrict__ abuf1,       // [B_, H_] bf16 pong
    const float* __restrict__ c0,             // [B_, H_] fp32
    float* __restrict__ out)                  // d_out base
{
    cg::grid_group grid = cg::this_grid();

    int blk  = blockIdx.x;        // 0..255
    int h0   = blk * 8;
    int tid  = threadIdx.x;
    int w    = tid >> 6;
    int kh   = w >> 1;            // K-quarter 0..3
    int gp   = w & 1;             // gate pair 0..1
    int lane = tid & 63;
    int c    = lane & 15;         // MFMA col: gate = gp*2 + (c>>3), h = h0 + (c&7)
    int q    = lane >> 4;

    // ---- weights -> registers (once) ----
    int gate = gp * 2 + (c >> 3);
    const unsigned short* wrow =
        Wab + (size_t)(gate * H_ + h0 + (c & 7)) * H_ + kh * 512 + q * 8;
    short8 wreg[16];
#pragma unroll
    for (int kq = 0; kq < 16; kq++)
        wreg[kq] = *(const short8*)(wrow + kq * 32);

    // ---- per-thread cell: thread <-> (bb, hl) mapping is static across steps
    int bb = tid >> 3;            // 0..63
    int hl = tid & 7;             // 0..7
    float c_reg = c0[bb * H_ + h0 + hl];

    __shared__ float yt[4][2][64][17];   // [kh][gp][m][col16], +1 pad

    for (int t = 0; t < T_; ++t) {
        const unsigned short* ap = (t & 1) ? abuf1 : abuf0;
        unsigned short*       an = (t & 1) ? abuf0 : abuf1;

        // ---- y = a_prev @ Wa^T for this wave's (kh, gp) slice ----
        const unsigned short* ab = ap + (size_t)c * H_ + kh * 512 + q * 8;
        f32x4 acc[4];
#pragma unroll
        for (int mt = 0; mt < 4; mt++) acc[mt] = (f32x4){0.f, 0.f, 0.f, 0.f};

#pragma unroll
        for (int kq = 0; kq < 16; kq++) {
#pragma unroll
            for (int mt = 0; mt < 4; mt++) {
                short8 af = *(const short8*)(ab + (size_t)mt * 16 * H_ + kq * 32);
                acc[mt] = __builtin_amdgcn_mfma_f32_16x16x32_bf16(
                    af, wreg[kq], acc[mt], 0, 0, 0);
            }
        }

        // ---- K-quarter partials -> LDS ----
#pragma unroll
        for (int mt = 0; mt < 4; mt++)
#pragma unroll
            for (int r = 0; r < 4; r++)
                yt[kh][gp][mt * 16 + q * 4 + r][c] = acc[mt][r];
        __syncthreads();

        // ---- fused activation: one cell (bb, hl) per thread ----
        long long oidx = ((long long)bb * T_ + t) * H_ + h0 + hl;
        float y[4];
#pragma unroll
        for (int g2 = 0; g2 < 4; g2++) {
            int cc  = (g2 & 1) * 8 + hl;
            int gpp = g2 >> 1;
            float v = yt[0][gpp][bb][cc] + yt[1][gpp][bb][cc] +
                      yt[2][gpp][bb][cc] + yt[3][gpp][bb][cc];
            v += out[(size_t)(2 + g2) * BTH_ + oidx];   // Yx + bias (precomputed)
            out[(size_t)(2 + g2) * BTH_ + oidx] = v;
            y[g2] = v;
        }
        float si = 1.f / (1.f + __expf(-y[0]));
        float sf = 1.f / (1.f + __expf(-y[1]));
        float so = 1.f / (1.f + __expf(-y[3]));
        float tg = tanhf(y[2]);
        c_reg = sf * c_reg + si * tg;
        float at = so * tanhf(c_reg);

        out[oidx]         = at;       // a slab
        out[BTH_ + oidx]  = c_reg;    // c slab
        an[bb * H_ + h0 + hl] = f32_to_bf16_rne(at);

        __threadfence();              // device-scope release (cross-XCD)
        grid.sync();                  // all blocks advance to step t+1 together
    }
}

extern "C" void kernel_launch(void* const* d_in, const int* in_sizes, int n_in,
                              void* d_out, int out_size, void* d_ws, size_t ws_size,
                              hipStream_t stream) {
    const float* x    = (const float*)d_in[0];   // [B,T,IN]
    const float* Wx   = (const float*)d_in[1];   // [4H,IN]
    const float* Wa   = (const float*)d_in[2];   // [4H,H]
    const float* bias = (const float*)d_in[3];   // [4H]
    const float* a0   = (const float*)d_in[4];   // [B,H]
    const float* c0   = (const float*)d_in[5];   // [B,H]
    float* out = (float*)d_out;

    // workspace layout (bf16 = unsigned short)
    unsigned short* xb    = (unsigned short*)d_ws;          // BT_*IN_
    unsigned short* wxb   = xb  + (size_t)BT_ * IN_;        // H4_*IN_
    unsigned short* wab   = wxb + (size_t)H4_ * IN_;        // H4_*H_
    unsigned short* abuf0 = wab + (size_t)H4_ * H_;         // B_*H_
    unsigned short* abuf1 = abuf0 + (size_t)B_ * H_;        // B_*H_

    cvt_bf16_kernel<<<2048, 256, 0, stream>>>(x,  xb,  (long)BT_ * IN_);
    cvt_bf16_kernel<<<2048, 256, 0, stream>>>(Wx, wxb, (long)H4_ * IN_);
    cvt_bf16_kernel<<<2048, 256, 0, stream>>>(Wa, wab, (long)H4_ * H_);
    cvt_bf16_kernel<<<128,  256, 0, stream>>>(a0, abuf0, (long)B_ * H_);

    gemm_yx<<<(BT_ / 128) * (H4_ / 128), 256, 0, stream>>>(xb, wxb, bias, out);

    const unsigned short* wab_c = wab;
    const float* c0_c = c0;
    void* kargs[5];
    kargs[0] = (void*)&wab_c;
    kargs[1] = (void*)&abuf0;
    kargs[2] = (void*)&abuf1;
    kargs[3] = (void*)&c0_c;
    kargs[4] = (void*)&out;
    hipLaunchCooperativeKernel((const void*)lstm_persistent,
                               dim3(256), dim3(512), kargs, 0, stream);
}